// Round 2
// baseline (1055.419 us; speedup 1.0000x reference)
//
#include <hip/hip_runtime.h>
#include <stdint.h>

#define N_NODES 50000
#define DIM_MEM 512
#define DIM_MSG 1280
#define N_MSG   100000

typedef __attribute__((ext_vector_type(8))) short bf16x8;
typedef __attribute__((ext_vector_type(4))) float f32x4;

__device__ __forceinline__ unsigned short f2bf(float f) {
  union { float f; uint32_t u; } v; v.f = f;
  uint32_t u = v.u;
  u += 0x7fffu + ((u >> 16) & 1u);   // round-to-nearest-even
  return (unsigned short)(u >> 16);
}

// ---------------- kernel 1: segment mean (seg_ids sorted) ----------------
// one wave per node; binary search for row range; f32 sums -> bf16 means
__global__ __launch_bounds__(64) void k_segmean(
    const float* __restrict__ msg, const int* __restrict__ seg,
    unsigned short* __restrict__ means, int* __restrict__ counts)
{
  int node = blockIdx.x;
  int lane = threadIdx.x;

  int lo = 0, hi = N_MSG;
  while (lo < hi) { int m = (lo + hi) >> 1; if (seg[m] < node) lo = m + 1; else hi = m; }
  int start = lo;
  hi = N_MSG;
  while (lo < hi) { int m = (lo + hi) >> 1; if (seg[m] < node + 1) lo = m + 1; else hi = m; }
  int end = lo;
  int cnt = end - start;
  if (lane == 0) counts[node] = cnt;

  float4 s[5];
#pragma unroll
  for (int j = 0; j < 5; j++) s[j] = make_float4(0.f, 0.f, 0.f, 0.f);
  const float4* m4 = (const float4*)msg;   // 320 float4 per row
  for (int r = start; r < end; r++) {
#pragma unroll
    for (int j = 0; j < 5; j++) {
      float4 v = m4[r * 320 + j * 64 + lane];
      s[j].x += v.x; s[j].y += v.y; s[j].z += v.z; s[j].w += v.w;
    }
  }
  float inv = (cnt > 0) ? 1.0f / (float)cnt : 0.0f;
  ushort4* o4 = (ushort4*)means;
#pragma unroll
  for (int j = 0; j < 5; j++) {
    ushort4 o;
    o.x = f2bf(s[j].x * inv); o.y = f2bf(s[j].y * inv);
    o.z = f2bf(s[j].z * inv); o.w = f2bf(s[j].w * inv);
    o4[node * 320 + j * 64 + lane] = o;
  }
}

// ---------------- kernel 2: f32 -> bf16 cast (vectorized) ----------------
__global__ __launch_bounds__(256) void k_cvt(
    const float* __restrict__ in, unsigned short* __restrict__ out, int n4)
{
  int i = blockIdx.x * 256 + threadIdx.x;
  if (i >= n4) return;
  float4 v = ((const float4*)in)[i];
  ushort4 o;
  o.x = f2bf(v.x); o.y = f2bf(v.y); o.z = f2bf(v.z); o.w = f2bf(v.w);
  ((ushort4*)out)[i] = o;
}

// ---------------- kernel 3: fused GEMM (6 strips) + GRU epilogue ----------------
// block tile: 128 rows x 64 output cols; 8 waves (2 row-groups x 4 col-groups)
// phase 1: means[128,1280] @ W_ih^T strips {r,z,n}   (K=1280)
// phase 2: memory[128,512] @ W_hh^T strips {r,z,n}   (K=512)
// acc[f][6] f32x4: 96 acc VGPR/thread
__global__ __launch_bounds__(512) void k_gru(
    const unsigned short* __restrict__ means, const unsigned short* __restrict__ memb,
    const unsigned short* __restrict__ wih,   const unsigned short* __restrict__ whh,
    const float* __restrict__ b_ih, const float* __restrict__ b_hh,
    const float* __restrict__ memory, const int* __restrict__ counts,
    float* __restrict__ out)
{
  // A: 1024 slots of 16B, slot s -> (kc = s>>7, row = s&127); addr = slot*16
  // B: 1536 slots of 16B, slot s -> (strip = s>>9, kc = (s>>6)&7, col = s&63)
  __shared__ unsigned short Al[1024 * 8];   // 16 KB
  __shared__ unsigned short Bl[1536 * 8];   // 24 KB

  int tid = threadIdx.x;
  int lane = tid & 63, wid = tid >> 6;
  int wr = wid >> 2, wc = wid & 3;          // wave: 64 rows x 16 cols
  int row0 = blockIdx.y * 128;
  int c0 = blockIdx.x * 64;

  f32x4 acc[4][6];
#pragma unroll
  for (int f = 0; f < 4; f++)
#pragma unroll
    for (int s = 0; s < 6; s++) acc[f][s] = (f32x4)(0.f);

  auto run_phase = [&](const unsigned short* __restrict__ Ag, int lda,
                       const unsigned short* __restrict__ Bg, int ldb,
                       int K, int so) {
    for (int k0 = 0; k0 < K; k0 += 64) {
      // ---- stage A tile [128 rows][64 k] via global_load_lds (linear dest) ----
#pragma unroll
      for (int i = 0; i < 2; i++) {
        int s = wid * 128 + i * 64 + lane;
        int row = s & 127, kc = s >> 7;
        int grow = row0 + row; if (grow > N_NODES - 1) grow = N_NODES - 1;
        const unsigned short* src = Ag + (size_t)grow * lda + k0 + kc * 8;
        __builtin_amdgcn_global_load_lds(
            (const __attribute__((address_space(1))) void*)src,
            (__attribute__((address_space(3))) void*)&Al[(wid * 128 + i * 64) * 8],
            16, 0, 0);
      }
      // ---- stage B tiles: 3 strips x [64 cols][64 k], slot = st*512 + kc*64 + col ----
#pragma unroll
      for (int i = 0; i < 3; i++) {
        int s = wid * 192 + i * 64 + lane;
        int st = s >> 9, r9 = s & 511;
        int kc = r9 >> 6, col = r9 & 63;     // FIX: was col=r9>>3, kc=r9&7 (scrambled B)
        const unsigned short* src = Bg + (size_t)(st * 512 + c0 + col) * ldb + k0 + kc * 8;
        __builtin_amdgcn_global_load_lds(
            (const __attribute__((address_space(1))) void*)src,
            (__attribute__((address_space(3))) void*)&Bl[(wid * 192 + i * 64) * 8],
            16, 0, 0);
      }
      __syncthreads();
      // ---- MFMA: 2 k-steps of 32 ----
      int g = lane >> 4, r = lane & 15;
#pragma unroll
      for (int t = 0; t < 2; t++) {
        bf16x8 a[4], b[3];
#pragma unroll
        for (int f = 0; f < 4; f++) {
          int slot = (t * 4 + g) * 128 + (wr * 64 + f * 16 + r);
          a[f] = *(const bf16x8*)&Al[slot * 8];
        }
#pragma unroll
        for (int st = 0; st < 3; st++) {
          int slot = (st * 8 + t * 4 + g) * 64 + (wc * 16 + r);
          b[st] = *(const bf16x8*)&Bl[slot * 8];
        }
#pragma unroll
        for (int f = 0; f < 4; f++)
#pragma unroll
          for (int st = 0; st < 3; st++)
            acc[f][so + st] = __builtin_amdgcn_mfma_f32_16x16x32_bf16(
                a[f], b[st], acc[f][so + st], 0, 0, 0);
      }
      __syncthreads();
    }
  };

  run_phase(means, DIM_MSG, wih, DIM_MSG, DIM_MSG, 0);  // i_r, i_z, i_n
  run_phase(memb,  DIM_MEM, whh, DIM_MEM, DIM_MEM, 3);  // h_r, h_z, h_n

  // ---- GRU epilogue ----
  int c = c0 + wc * 16 + (lane & 15);
  float bir = b_ih[c], biz = b_ih[512 + c], bin = b_ih[1024 + c];
  float bhr = b_hh[c], bhz = b_hh[512 + c], bhn = b_hh[1024 + c];
  int g = lane >> 4;
#pragma unroll
  for (int f = 0; f < 4; f++) {
    int rbase = row0 + wr * 64 + f * 16 + g * 4;
#pragma unroll
    for (int rr = 0; rr < 4; rr++) {
      int row = rbase + rr;
      if (row < N_NODES) {
        float ir = acc[f][0][rr] + bir, iz = acc[f][1][rr] + biz, inn = acc[f][2][rr] + bin;
        float hr = acc[f][3][rr] + bhr, hz = acc[f][4][rr] + bhz, hn = acc[f][5][rr] + bhn;
        float rg = 1.f / (1.f + __expf(-(ir + hr)));
        float zg = 1.f / (1.f + __expf(-(iz + hz)));
        float cd = tanhf(inn + rg * hn);
        float h = memory[(size_t)row * DIM_MEM + c];
        float o = (counts[row] > 0) ? (1.f - zg) * cd + zg * h : h;
        out[(size_t)row * DIM_MEM + c] = o;
      }
    }
  }
}

// ---------------- launch ----------------
extern "C" void kernel_launch(void* const* d_in, const int* in_sizes, int n_in,
                              void* d_out, int out_size, void* d_ws, size_t ws_size,
                              hipStream_t stream) {
  const float* msg  = (const float*)d_in[0];
  const int*   seg  = (const int*)d_in[1];
  const float* mem  = (const float*)d_in[2];
  const float* W_ih = (const float*)d_in[3];
  const float* W_hh = (const float*)d_in[4];
  const float* b_ih = (const float*)d_in[5];
  const float* b_hh = (const float*)d_in[6];
  float* out = (float*)d_out;

  char* ws = (char*)d_ws;
  unsigned short* means = (unsigned short*)(ws);                     // 128,000,000 B
  unsigned short* memb  = (unsigned short*)(ws + 128000000LL);       //  51,200,000 B
  unsigned short* wihb  = (unsigned short*)(ws + 179200000LL);       //   3,932,160 B
  unsigned short* whhb  = (unsigned short*)(ws + 183132160LL);       //   1,572,864 B
  int* counts           = (int*)(ws + 184705024LL);                  //     200,000 B

  k_segmean<<<N_NODES, 64, 0, stream>>>(msg, seg, means, counts);
  k_cvt<<<(N_NODES * DIM_MEM / 4 + 255) / 256, 256, 0, stream>>>(mem, memb, N_NODES * DIM_MEM / 4);
  k_cvt<<<(3 * DIM_MEM * DIM_MSG / 4 + 255) / 256, 256, 0, stream>>>(W_ih, wihb, 3 * DIM_MEM * DIM_MSG / 4);
  k_cvt<<<(3 * DIM_MEM * DIM_MEM / 4 + 255) / 256, 256, 0, stream>>>(W_hh, whhb, 3 * DIM_MEM * DIM_MEM / 4);

  dim3 grid(8, (N_NODES + 127) / 128, 1);   // 8 col-tiles x 391 row-tiles
  k_gru<<<grid, 512, 0, stream>>>(means, memb, wihb, whhb, b_ih, b_hh, mem, counts, out);
}

// Round 3
// 1024.401 us; speedup vs baseline: 1.0303x; 1.0303x over previous
//
#include <hip/hip_runtime.h>
#include <stdint.h>

#define N_NODES 50000
#define DIM_MEM 512
#define DIM_MSG 1280
#define N_MSG   100000

typedef __attribute__((ext_vector_type(8))) short bf16x8;
typedef __attribute__((ext_vector_type(4))) float f32x4;

template <int N> struct ic { static constexpr int v = N; };

__device__ __forceinline__ unsigned short f2bf(float f) {
  union { float f; uint32_t u; } v; v.f = f;
  uint32_t u = v.u;
  u += 0x7fffu + ((u >> 16) & 1u);   // round-to-nearest-even
  return (unsigned short)(u >> 16);
}

// ---------------- kernel 1: segment mean (seg_ids sorted) ----------------
__global__ __launch_bounds__(64) void k_segmean(
    const float* __restrict__ msg, const int* __restrict__ seg,
    unsigned short* __restrict__ means, int* __restrict__ counts)
{
  int node = blockIdx.x;
  int lane = threadIdx.x;

  int lo = 0, hi = N_MSG;
  while (lo < hi) { int m = (lo + hi) >> 1; if (seg[m] < node) lo = m + 1; else hi = m; }
  int start = lo;
  hi = N_MSG;
  while (lo < hi) { int m = (lo + hi) >> 1; if (seg[m] < node + 1) lo = m + 1; else hi = m; }
  int end = lo;
  int cnt = end - start;
  if (lane == 0) counts[node] = cnt;

  float4 s[5];
#pragma unroll
  for (int j = 0; j < 5; j++) s[j] = make_float4(0.f, 0.f, 0.f, 0.f);
  const float4* m4 = (const float4*)msg;   // 320 float4 per row
  for (int r = start; r < end; r++) {
#pragma unroll
    for (int j = 0; j < 5; j++) {
      float4 v = m4[r * 320 + j * 64 + lane];
      s[j].x += v.x; s[j].y += v.y; s[j].z += v.z; s[j].w += v.w;
    }
  }
  float inv = (cnt > 0) ? 1.0f / (float)cnt : 0.0f;
  ushort4* o4 = (ushort4*)means;
#pragma unroll
  for (int j = 0; j < 5; j++) {
    ushort4 o;
    o.x = f2bf(s[j].x * inv); o.y = f2bf(s[j].y * inv);
    o.z = f2bf(s[j].z * inv); o.w = f2bf(s[j].w * inv);
    o4[node * 320 + j * 64 + lane] = o;
  }
}

// ---------------- kernel 2: f32 -> bf16 cast ----------------
__global__ __launch_bounds__(256) void k_cvt(
    const float* __restrict__ in, unsigned short* __restrict__ out, int n4)
{
  int i = blockIdx.x * 256 + threadIdx.x;
  if (i >= n4) return;
  float4 v = ((const float4*)in)[i];
  ushort4 o;
  o.x = f2bf(v.x); o.y = f2bf(v.y); o.z = f2bf(v.z); o.w = f2bf(v.w);
  ((ushort4*)out)[i] = o;
}

// ---------------- kernel 3: fused GEMM (6 strips) + GRU epilogue ----------------
// 2-phase double-buffered pipeline (T3-min): stage chunk c+1 into buf^1 while
// computing chunk c from buf; one __syncthreads per chunk (vmcnt drain lands
// AFTER the MFMAs, overlapping load latency with compute).
// 28 K-chunks total: 0..19 = means@W_ih^T (K=1280), 20..27 = memb@W_hh^T (K=512).
__global__ __launch_bounds__(512) void k_gru(
    const unsigned short* __restrict__ means, const unsigned short* __restrict__ memb,
    const unsigned short* __restrict__ wih,   const unsigned short* __restrict__ whh,
    const float* __restrict__ b_ih, const float* __restrict__ b_hh,
    const float* __restrict__ memory, const int* __restrict__ counts,
    float* __restrict__ out)
{
  __shared__ unsigned short Al[2][1024 * 8];   // 2 x 16 KB
  __shared__ unsigned short Bl[2][1536 * 8];   // 2 x 24 KB

  int tid = threadIdx.x;
  int lane = tid & 63, wid = tid >> 6;
  int wr = wid >> 2, wc = wid & 3;          // wave: 64 rows x 16 cols
  int row0 = blockIdx.y * 128;
  int c0 = blockIdx.x * 64;

  f32x4 acc[4][6];
#pragma unroll
  for (int f = 0; f < 4; f++)
#pragma unroll
    for (int s = 0; s < 6; s++) acc[f][s] = (f32x4)(0.f);

  // stage chunk c into LDS buffer pb
  auto stage = [&](int c, int pb) {
    const unsigned short* Ag; const unsigned short* Bg; int ld, k0;
    if (c < 20) { Ag = means; Bg = wih; ld = DIM_MSG; k0 = c * 64; }
    else        { Ag = memb;  Bg = whh; ld = DIM_MEM; k0 = (c - 20) * 64; }
#pragma unroll
    for (int i = 0; i < 2; i++) {
      int s = wid * 128 + i * 64 + lane;
      int row = s & 127, kc = s >> 7;
      int grow = row0 + row; if (grow > N_NODES - 1) grow = N_NODES - 1;
      const unsigned short* src = Ag + (size_t)grow * ld + k0 + kc * 8;
      __builtin_amdgcn_global_load_lds(
          (const __attribute__((address_space(1))) void*)src,
          (__attribute__((address_space(3))) void*)&Al[pb][(wid * 128 + i * 64) * 8],
          16, 0, 0);
    }
#pragma unroll
    for (int i = 0; i < 3; i++) {
      int s = wid * 192 + i * 64 + lane;
      int st = s >> 9, r9 = s & 511;
      int kc = r9 >> 6, col = r9 & 63;
      const unsigned short* src = Bg + (size_t)(st * 512 + c0 + col) * ld + k0 + kc * 8;
      __builtin_amdgcn_global_load_lds(
          (const __attribute__((address_space(1))) void*)src,
          (__attribute__((address_space(3))) void*)&Bl[pb][(wid * 192 + i * 64) * 8],
          16, 0, 0);
    }
  };

  // compute chunk from buffer pb; SO = accumulator strip offset (compile-time)
  auto compute = [&](int pb, auto SO) {
    constexpr int so = decltype(SO)::v;
    int g = lane >> 4, r = lane & 15;
#pragma unroll
    for (int t = 0; t < 2; t++) {
      bf16x8 a[4], b[3];
#pragma unroll
      for (int f = 0; f < 4; f++) {
        int slot = (t * 4 + g) * 128 + (wr * 64 + f * 16 + r);
        a[f] = *(const bf16x8*)&Al[pb][slot * 8];
      }
#pragma unroll
      for (int st = 0; st < 3; st++) {
        int slot = (st * 8 + t * 4 + g) * 64 + (wc * 16 + r);
        b[st] = *(const bf16x8*)&Bl[pb][slot * 8];
      }
#pragma unroll
      for (int f = 0; f < 4; f++)
#pragma unroll
        for (int st = 0; st < 3; st++)
          acc[f][so + st] = __builtin_amdgcn_mfma_f32_16x16x32_bf16(
              a[f], b[st], acc[f][so + st], 0, 0, 0);
    }
  };

  stage(0, 0);
  __syncthreads();
  int cur = 0;
  for (int c = 0; c < 20; ++c) {           // phase 1: i_r, i_z, i_n
    stage(c + 1, cur ^ 1);                 // c=19 stages chunk 20 (phase 2) - ok
    compute(cur, ic<0>{});
    __syncthreads();
    cur ^= 1;
  }
  for (int c = 20; c < 28; ++c) {          // phase 2: h_r, h_z, h_n
    if (c < 27) stage(c + 1, cur ^ 1);
    compute(cur, ic<3>{});
    __syncthreads();
    cur ^= 1;
  }

  // ---- GRU epilogue ----
  int c = c0 + wc * 16 + (lane & 15);
  float bir = b_ih[c], biz = b_ih[512 + c], bin = b_ih[1024 + c];
  float bhr = b_hh[c], bhz = b_hh[512 + c], bhn = b_hh[1024 + c];
  int g = lane >> 4;
#pragma unroll
  for (int f = 0; f < 4; f++) {
    int rbase = row0 + wr * 64 + f * 16 + g * 4;
#pragma unroll
    for (int rr = 0; rr < 4; rr++) {
      int row = rbase + rr;
      if (row < N_NODES) {
        float ir = acc[f][0][rr] + bir, iz = acc[f][1][rr] + biz, inn = acc[f][2][rr] + bin;
        float hr = acc[f][3][rr] + bhr, hz = acc[f][4][rr] + bhz, hn = acc[f][5][rr] + bhn;
        float rg = 1.f / (1.f + __expf(-(ir + hr)));
        float zg = 1.f / (1.f + __expf(-(iz + hz)));
        float cd = tanhf(inn + rg * hn);
        float h = memory[(size_t)row * DIM_MEM + c];
        float o = (counts[row] > 0) ? (1.f - zg) * cd + zg * h : h;
        out[(size_t)row * DIM_MEM + c] = o;
      }
    }
  }
}

// ---------------- launch ----------------
extern "C" void kernel_launch(void* const* d_in, const int* in_sizes, int n_in,
                              void* d_out, int out_size, void* d_ws, size_t ws_size,
                              hipStream_t stream) {
  const float* msg  = (const float*)d_in[0];
  const int*   seg  = (const int*)d_in[1];
  const float* mem  = (const float*)d_in[2];
  const float* W_ih = (const float*)d_in[3];
  const float* W_hh = (const float*)d_in[4];
  const float* b_ih = (const float*)d_in[5];
  const float* b_hh = (const float*)d_in[6];
  float* out = (float*)d_out;

  char* ws = (char*)d_ws;
  unsigned short* means = (unsigned short*)(ws);                     // 128,000,000 B
  unsigned short* memb  = (unsigned short*)(ws + 128000000LL);       //  51,200,000 B
  unsigned short* wihb  = (unsigned short*)(ws + 179200000LL);       //   3,932,160 B
  unsigned short* whhb  = (unsigned short*)(ws + 183132160LL);       //   1,572,864 B
  int* counts           = (int*)(ws + 184705024LL);                  //     200,000 B

  k_segmean<<<N_NODES, 64, 0, stream>>>(msg, seg, means, counts);
  k_cvt<<<(N_NODES * DIM_MEM / 4 + 255) / 256, 256, 0, stream>>>(mem, memb, N_NODES * DIM_MEM / 4);
  k_cvt<<<(3 * DIM_MEM * DIM_MSG / 4 + 255) / 256, 256, 0, stream>>>(W_ih, wihb, 3 * DIM_MEM * DIM_MSG / 4);
  k_cvt<<<(3 * DIM_MEM * DIM_MEM / 4 + 255) / 256, 256, 0, stream>>>(W_hh, whhb, 3 * DIM_MEM * DIM_MEM / 4);

  dim3 grid(8, (N_NODES + 127) / 128, 1);   // blockIdx.x = col-tile = XCD (bid%8)
  k_gru<<<grid, 512, 0, stream>>>(means, memb, wihb, whhb, b_ih, b_hh, mem, counts, out);
}

// Round 4
// 1019.977 us; speedup vs baseline: 1.0347x; 1.0043x over previous
//
#include <hip/hip_runtime.h>
#include <stdint.h>

#define N_NODES 50000
#define DIM_MEM 512
#define DIM_MSG 1280
#define N_MSG   100000

typedef __attribute__((ext_vector_type(8))) short bf16x8;
typedef __attribute__((ext_vector_type(4))) float f32x4;

template <int N> struct ic { static constexpr int v = N; };

// counted vmcnt wait + scheduler fence (rule #18)
#define WAITV(n) do { asm volatile("s_waitcnt vmcnt(" #n ")" ::: "memory"); \
                      __builtin_amdgcn_sched_barrier(0); } while (0)
#define WAITL0() do { asm volatile("s_waitcnt lgkmcnt(0)" ::: "memory"); \
                      __builtin_amdgcn_sched_barrier(0); } while (0)

__device__ __forceinline__ unsigned short f2bf(float f) {
  union { float f; uint32_t u; } v; v.f = f;
  uint32_t u = v.u;
  u += 0x7fffu + ((u >> 16) & 1u);   // round-to-nearest-even
  return (unsigned short)(u >> 16);
}

// ---------------- kernel 1: segment mean (seg_ids sorted) ----------------
__global__ __launch_bounds__(64) void k_segmean(
    const float* __restrict__ msg, const int* __restrict__ seg,
    unsigned short* __restrict__ means, int* __restrict__ counts)
{
  int node = blockIdx.x;
  int lane = threadIdx.x;

  int lo = 0, hi = N_MSG;
  while (lo < hi) { int m = (lo + hi) >> 1; if (seg[m] < node) lo = m + 1; else hi = m; }
  int start = lo;
  hi = N_MSG;
  while (lo < hi) { int m = (lo + hi) >> 1; if (seg[m] < node + 1) lo = m + 1; else hi = m; }
  int end = lo;
  int cnt = end - start;
  if (lane == 0) counts[node] = cnt;

  float4 s[5];
#pragma unroll
  for (int j = 0; j < 5; j++) s[j] = make_float4(0.f, 0.f, 0.f, 0.f);
  const float4* m4 = (const float4*)msg;   // 320 float4 per row
  for (int r = start; r < end; r++) {
#pragma unroll
    for (int j = 0; j < 5; j++) {
      float4 v = m4[r * 320 + j * 64 + lane];
      s[j].x += v.x; s[j].y += v.y; s[j].z += v.z; s[j].w += v.w;
    }
  }
  float inv = (cnt > 0) ? 1.0f / (float)cnt : 0.0f;
  ushort4* o4 = (ushort4*)means;
#pragma unroll
  for (int j = 0; j < 5; j++) {
    ushort4 o;
    o.x = f2bf(s[j].x * inv); o.y = f2bf(s[j].y * inv);
    o.z = f2bf(s[j].z * inv); o.w = f2bf(s[j].w * inv);
    o4[node * 320 + j * 64 + lane] = o;
  }
}

// ---------------- kernel 2: f32 -> bf16 cast ----------------
__global__ __launch_bounds__(256) void k_cvt(
    const float* __restrict__ in, unsigned short* __restrict__ out, int n4)
{
  int i = blockIdx.x * 256 + threadIdx.x;
  if (i >= n4) return;
  float4 v = ((const float4*)in)[i];
  ushort4 o;
  o.x = f2bf(v.x); o.y = f2bf(v.y); o.z = f2bf(v.z); o.w = f2bf(v.w);
  ((ushort4*)out)[i] = o;
}

// ---------------- kernel 3: fused GEMM (6 strips) + GRU epilogue ----------------
// T4 pipeline: 3-buffer LDS ring, 2 chunks prefetched ahead, counted vmcnt
// (never 0 in steady state), raw s_barrier. Per stage = 5 global_load_lds /wave;
// with chunks c,c+1,c+2 in flight, vmcnt(10) == "chunk c landed".
// 28 K-chunks: 0..19 = means@W_ih^T (K=1280), 20..27 = memb@W_hh^T (K=512).
__global__ __launch_bounds__(512) void k_gru(
    const unsigned short* __restrict__ means, const unsigned short* __restrict__ memb,
    const unsigned short* __restrict__ wih,   const unsigned short* __restrict__ whh,
    const float* __restrict__ b_ih, const float* __restrict__ b_hh,
    const float* __restrict__ memory, const int* __restrict__ counts,
    float* __restrict__ out)
{
  __shared__ unsigned short Al[3][1024 * 8];   // 3 x 16 KB
  __shared__ unsigned short Bl[3][1536 * 8];   // 3 x 24 KB   (120 KB total)

  int tid = threadIdx.x;
  int lane = tid & 63, wid = tid >> 6;
  int wr = wid >> 2, wc = wid & 3;          // wave: 64 rows x 16 cols
  int row0 = blockIdx.y * 128;
  int c0 = blockIdx.x * 64;

  f32x4 acc[4][6];
#pragma unroll
  for (int f = 0; f < 4; f++)
#pragma unroll
    for (int s = 0; s < 6; s++) acc[f][s] = (f32x4)(0.f);

  // stage chunk c into LDS ring buffer pb (5 global_load_lds per wave)
  auto stage = [&](int c, int pb) {
    const unsigned short* Ag; const unsigned short* Bg; int ld, k0;
    if (c < 20) { Ag = means; Bg = wih; ld = DIM_MSG; k0 = c * 64; }
    else        { Ag = memb;  Bg = whh; ld = DIM_MEM; k0 = (c - 20) * 64; }
#pragma unroll
    for (int i = 0; i < 2; i++) {
      int s = wid * 128 + i * 64 + lane;
      int row = s & 127, kc = s >> 7;
      int grow = row0 + row; if (grow > N_NODES - 1) grow = N_NODES - 1;
      const unsigned short* src = Ag + (size_t)grow * ld + k0 + kc * 8;
      __builtin_amdgcn_global_load_lds(
          (const __attribute__((address_space(1))) void*)src,
          (__attribute__((address_space(3))) void*)&Al[pb][(wid * 128 + i * 64) * 8],
          16, 0, 0);
    }
#pragma unroll
    for (int i = 0; i < 3; i++) {
      int s = wid * 192 + i * 64 + lane;
      int st = s >> 9, r9 = s & 511;
      int kc = r9 >> 6, col = r9 & 63;
      const unsigned short* src = Bg + (size_t)(st * 512 + c0 + col) * ld + k0 + kc * 8;
      __builtin_amdgcn_global_load_lds(
          (const __attribute__((address_space(1))) void*)src,
          (__attribute__((address_space(3))) void*)&Bl[pb][(wid * 192 + i * 64) * 8],
          16, 0, 0);
    }
  };

  // compute chunk from ring buffer pb; SO = acc strip offset (compile-time)
  auto compute = [&](int pb, auto SO) {
    constexpr int so = decltype(SO)::v;
    int g = lane >> 4, r = lane & 15;
#pragma unroll
    for (int t = 0; t < 2; t++) {
      bf16x8 a[4], b[3];
#pragma unroll
      for (int f = 0; f < 4; f++) {
        int slot = (t * 4 + g) * 128 + (wr * 64 + f * 16 + r);
        a[f] = *(const bf16x8*)&Al[pb][slot * 8];
      }
#pragma unroll
      for (int st = 0; st < 3; st++) {
        int slot = (st * 8 + t * 4 + g) * 64 + (wc * 16 + r);
        b[st] = *(const bf16x8*)&Bl[pb][slot * 8];
      }
      __builtin_amdgcn_s_setprio(1);
#pragma unroll
      for (int f = 0; f < 4; f++)
#pragma unroll
        for (int st = 0; st < 3; st++)
          acc[f][so + st] = __builtin_amdgcn_mfma_f32_16x16x32_bf16(
              a[f], b[st], acc[f][so + st], 0, 0, 0);
      __builtin_amdgcn_s_setprio(0);
    }
  };

  // prologue: 2 chunks in flight
  stage(0, 0);
  stage(1, 1);
  // phase 1 (chunks 0..19, strips i_r/i_z/i_n); c+2 <= 21 so always stage
  for (int c = 0; c < 20; ++c) {
    stage(c + 2, (c + 2) % 3);
    WAITV(10);                               // chunk c landed; 10 still in flight
    __builtin_amdgcn_s_barrier();
    compute(c % 3, ic<0>{});
    WAITL0();
    __builtin_amdgcn_s_barrier();            // WAR: ring slot c%3 free for c+3
  }
  // phase 2 (chunks 20..27, strips h_r/h_z/h_n)
  for (int c = 20; c < 28; ++c) {
    if (c <= 25)      { stage(c + 2, (c + 2) % 3); WAITV(10); }
    else if (c == 26) { WAITV(5); }
    else              { WAITV(0); }
    __builtin_amdgcn_s_barrier();
    compute(c % 3, ic<3>{});
    WAITL0();
    __builtin_amdgcn_s_barrier();
  }

  // ---- GRU epilogue ----
  int c = c0 + wc * 16 + (lane & 15);
  float bir = b_ih[c], biz = b_ih[512 + c], bin = b_ih[1024 + c];
  float bhr = b_hh[c], bhz = b_hh[512 + c], bhn = b_hh[1024 + c];
  int g = lane >> 4;
#pragma unroll
  for (int f = 0; f < 4; f++) {
    int rbase = row0 + wr * 64 + f * 16 + g * 4;
#pragma unroll
    for (int rr = 0; rr < 4; rr++) {
      int row = rbase + rr;
      if (row < N_NODES) {
        float ir = acc[f][0][rr] + bir, iz = acc[f][1][rr] + biz, inn = acc[f][2][rr] + bin;
        float hr = acc[f][3][rr] + bhr, hz = acc[f][4][rr] + bhz, hn = acc[f][5][rr] + bhn;
        float rg = 1.f / (1.f + __expf(-(ir + hr)));
        float zg = 1.f / (1.f + __expf(-(iz + hz)));
        float cd = tanhf(inn + rg * hn);
        float h = memory[(size_t)row * DIM_MEM + c];
        float o = (counts[row] > 0) ? (1.f - zg) * cd + zg * h : h;
        out[(size_t)row * DIM_MEM + c] = o;
      }
    }
  }
}

// ---------------- launch ----------------
extern "C" void kernel_launch(void* const* d_in, const int* in_sizes, int n_in,
                              void* d_out, int out_size, void* d_ws, size_t ws_size,
                              hipStream_t stream) {
  const float* msg  = (const float*)d_in[0];
  const int*   seg  = (const int*)d_in[1];
  const float* mem  = (const float*)d_in[2];
  const float* W_ih = (const float*)d_in[3];
  const float* W_hh = (const float*)d_in[4];
  const float* b_ih = (const float*)d_in[5];
  const float* b_hh = (const float*)d_in[6];
  float* out = (float*)d_out;

  char* ws = (char*)d_ws;
  unsigned short* means = (unsigned short*)(ws);                     // 128,000,000 B
  unsigned short* memb  = (unsigned short*)(ws + 128000000LL);       //  51,200,000 B
  unsigned short* wihb  = (unsigned short*)(ws + 179200000LL);       //   3,932,160 B
  unsigned short* whhb  = (unsigned short*)(ws + 183132160LL);       //   1,572,864 B
  int* counts           = (int*)(ws + 184705024LL);                  //     200,000 B

  k_segmean<<<N_NODES, 64, 0, stream>>>(msg, seg, means, counts);
  k_cvt<<<(N_NODES * DIM_MEM / 4 + 255) / 256, 256, 0, stream>>>(mem, memb, N_NODES * DIM_MEM / 4);
  k_cvt<<<(3 * DIM_MEM * DIM_MSG / 4 + 255) / 256, 256, 0, stream>>>(W_ih, wihb, 3 * DIM_MEM * DIM_MSG / 4);
  k_cvt<<<(3 * DIM_MEM * DIM_MEM / 4 + 255) / 256, 256, 0, stream>>>(W_hh, whhb, 3 * DIM_MEM * DIM_MEM / 4);

  dim3 grid(8, (N_NODES + 127) / 128, 1);   // blockIdx.x = col-tile = XCD (bid%8)
  k_gru<<<grid, 512, 0, stream>>>(means, memb, wihb, whhb, b_ih, b_hh, mem, counts, out);
}